// Round 20
// baseline (205.861 us; speedup 1.0000x reference)
//
#include <hip/hip_runtime.h>
#include <hip/hip_bf16.h>
#include <stdint.h>

typedef __attribute__((ext_vector_type(8))) short bf16x8;
typedef __attribute__((ext_vector_type(16))) float f32x16;
using bf16 = __hip_bfloat16;

static constexpr int Mdim = 512;   // A batch
static constexpr int Ndim = 64;    // B batch
static constexpr int Cdim = 128;   // channels (K of the GEMM)
static constexpr int Pdim = 64;    // H*W positions
static constexpr float EPS_ADD = 0.001f;

#define SB0 __builtin_amdgcn_sched_barrier(0)

// ---------------------------------------------------------------------------
// async global->LDS, 16B per lane
// ---------------------------------------------------------------------------
__device__ __forceinline__ void gll16(const void* gsrc, void* ldst) {
    const __attribute__((address_space(1))) unsigned int* g =
        (const __attribute__((address_space(1))) unsigned int*)gsrc;
    __attribute__((address_space(3))) unsigned int* l =
        (__attribute__((address_space(3))) unsigned int*)(uintptr_t)ldst;
    __builtin_amdgcn_global_load_lds(g, l, 16, 0, 0);
}

// ---------------------------------------------------------------------------
// prep (fused, UNCHANGED — verified): fragment-ordered outputs.
// ---------------------------------------------------------------------------
__global__ void prep_kernel(const float* __restrict__ A, const float* __restrict__ B,
                            const float* __restrict__ Wg,
                            bf16* __restrict__ Afrag, bf16* __restrict__ Gfrag) {
    __shared__ float lds[128 * 65];
    const int t = threadIdx.x;

    if (blockIdx.x < 512) {
        const int m = blockIdx.x;
        const float* __restrict__ Am = A + (size_t)m * (Cdim * Pdim);
#pragma unroll
        for (int i = 0; i < 8; ++i) {
            int v = t + i * 256;
            int gidx = v * 4;
            int c = gidx >> 6, p = gidx & 63;
            float4 val = *reinterpret_cast<const float4*>(Am + gidx);
            float* dst = &lds[c * 65 + p];
            dst[0] = val.x; dst[1] = val.y; dst[2] = val.z; dst[3] = val.w;
        }
        __syncthreads();

        unsigned* __restrict__ dst32 = (unsigned*)(Afrag + (size_t)m * 8192);
#pragma unroll
        for (int i = 0; i < 16; ++i) {
            int pr = t + i * 256;
            int p = pr >> 6;
            int c = (pr & 63) << 1;
            float f0 = lds[c * 65 + p];
            float f1 = lds[(c + 1) * 65 + p];
            union { bf16 hh[2]; unsigned u; } pk;
            pk.hh[0] = __float2bfloat16(f0);
            pk.hh[1] = __float2bfloat16(f1);
            int h = p >> 5, l31 = p & 31;
            int ks = c >> 4, hi = (c >> 3) & 1, e = c & 7;
            dst32[h * 2048 + ks * 256 + hi * 128 + l31 * 4 + (e >> 1)] = pk.u;
        }
    } else {
        const int nb = blockIdx.x - 512;
        const int n  = nb >> 2;
        const int q0 = (nb & 3) * 16;
        const float* __restrict__ Bn = B + (size_t)n * (Cdim * Pdim);
#pragma unroll
        for (int i = 0; i < 8; ++i) {
            int v = t + i * 256;
            int gidx = v * 4;
            int c = gidx >> 6, q = gidx & 63;
            float4 val = *reinterpret_cast<const float4*>(Bn + gidx);
            float* dst = &lds[c * 65 + q];
            dst[0] = val.x; dst[1] = val.y; dst[2] = val.z; dst[3] = val.w;
        }
        __syncthreads();

        const int d  = t & 127;
        const int qb = q0 + (t >> 7) * 8;
        float acc[8] = {0.f, 0.f, 0.f, 0.f, 0.f, 0.f, 0.f, 0.f};
        for (int c = 0; c < 128; ++c) {
            float w = Wg[c * 128 + d];
#pragma unroll
            for (int qi = 0; qi < 8; ++qi)
                acc[qi] = fmaf(lds[c * 65 + qb + qi], w, acc[qi]);
        }
        bf16* __restrict__ gdst = Gfrag + (size_t)n * 8192;
        const int ks = d >> 4, hi = (d >> 3) & 1, e = d & 7;
#pragma unroll
        for (int qi = 0; qi < 8; ++qi) {
            int q = qb + qi;
            int qt = q >> 5, l31 = q & 31;
            gdst[qt * 4096 + ks * 512 + hi * 256 + l31 * 8 + e] = __float2bfloat16(acc[qi]);
        }
    }
}

// ---------------------------------------------------------------------------
// gemm_probe<V>: ablation of the v16 structure (rule #17: subtracted phases
// keep their inputs live via value-consumption, not bare skips).
//   V=0: full v16, REP=1, writes the real output (launched LAST).
//   V=1: no MFMA   — ds_reads consumed via XOR into acc[0]; reduce/store kept.
//   V=2: no ds_read — gf = A-register copies; MFMA/stage/epilogue kept.
//   V=3: no stage  — zero gll16; ds_reads of stale LDS; rest kept.
// Probes REP=4 (rise above the harness fill kernels in rocprof top-5);
// probe stores are garbage but V0 overwrites every d_out element afterward.
// ---------------------------------------------------------------------------
template<int V>
__global__ __launch_bounds__(256, 2)
void gemm_probe(const bf16* __restrict__ Afrag, const bf16* __restrict__ Gfrag,
                float* __restrict__ out) {
    constexpr int REP = (V == 0) ? 1 : 4;
    __shared__ bf16 sG[3][8192];
    const int tid  = threadIdx.x;
    const int lane = tid & 63;
    const int wv   = tid >> 6;
    const int mi = wv >> 1, h = wv & 1;
    const int l31 = lane & 31, hi = lane >> 5;
    const int mg = blockIdx.x & 127;
    const int bn = blockIdx.x >> 7;
    const int m0 = mg * 4 + mi * 2;

    bf16x8 a[2][8];
#pragma unroll
    for (int u = 0; u < 2; ++u) {
        const bf16* Ap = Afrag + (size_t)(m0 + u) * 8192 + h * 4096 + lane * 8;
#pragma unroll
        for (int ks = 0; ks < 8; ++ks)
            a[u][ks] = *reinterpret_cast<const bf16x8*>(Ap + ks * 512);
    }
    asm volatile("" ::: "memory");

    const char* Gsrc = (const char*)(Gfrag + (size_t)(bn * 16) * 8192);
    auto stageG = [&](int s) {
        if constexpr (V == 3) return;
        char* dst = (char*)&sG[s % 3][0];
        const char* src = Gsrc + (size_t)s * 16384;
#pragma unroll
        for (int i = 0; i < 4; ++i) {
            int f = (i * 256 + tid) * 16;
            gll16(src + f, dst + f);
        }
    };

    const f32x16 z16 = {0.f,0.f,0.f,0.f,0.f,0.f,0.f,0.f,0.f,0.f,0.f,0.f,0.f,0.f,0.f,0.f};
    f32x16 acc0, acc1;
    bf16x8 gfA[8], gfB[8];

    if constexpr (V == 1) {   // opaque acc init once (reduce stays per-body live)
#pragma unroll
        for (int j = 0; j < 16; ++j) {
            float t0 = 0.f, t1 = 0.f;
            asm volatile("" : "+v"(t0), "+v"(t1));
            acc0[j] = t0; acc1[j] = t1;
        }
    }

    auto ldgf = [&](bf16x8 (&g)[8], const char* base) {
        if constexpr (V == 2) {
#pragma unroll
            for (int ks = 0; ks < 8; ++ks) g[ks] = a[0][ks];
        } else {
#pragma unroll
            for (int ks = 0; ks < 8; ++ks)
                g[ks] = *reinterpret_cast<const bf16x8*>(base + ks * 1024);
        }
    };
    auto mmcl = [&](const bf16x8 (&gf)[8], int salt) {
        if constexpr (V == 1) {
            unsigned kx = (unsigned)salt;
#pragma unroll
            for (int ks = 0; ks < 8; ++ks)
                kx ^= *reinterpret_cast<const unsigned*>(&gf[ks]);   // forces loads complete
            acc0[0] = __builtin_bit_cast(float, kx);
            acc1[0] = __builtin_bit_cast(float, kx ^ 0x55555555u);
        } else {
            __builtin_amdgcn_s_setprio(1);
            acc0 = __builtin_amdgcn_mfma_f32_32x32x16_bf16(gf[0], a[0][0], z16, 0, 0, 0);
            acc1 = __builtin_amdgcn_mfma_f32_32x32x16_bf16(gf[0], a[1][0], z16, 0, 0, 0);
#pragma unroll
            for (int ks = 1; ks < 8; ++ks) {
                acc0 = __builtin_amdgcn_mfma_f32_32x32x16_bf16(gf[ks], a[0][ks], acc0, 0, 0, 0);
                acc1 = __builtin_amdgcn_mfma_f32_32x32x16_bf16(gf[ks], a[1][ks], acc1, 0, 0, 0);
            }
            __builtin_amdgcn_s_setprio(0);
        }
    };
    auto red16 = [&](const f32x16& v) -> float {
        float x0 = fmaxf(v[0], v[1]),  x1 = fmaxf(v[2], v[3]);
        float x2 = fmaxf(v[4], v[5]),  x3 = fmaxf(v[6], v[7]);
        float x4 = fmaxf(v[8], v[9]),  x5 = fmaxf(v[10], v[11]);
        float x6 = fmaxf(v[12], v[13]), x7 = fmaxf(v[14], v[15]);
        x0 = fmaxf(x0, x1); x2 = fmaxf(x2, x3);
        x4 = fmaxf(x4, x5); x6 = fmaxf(x6, x7);
        return fmaxf(fmaxf(x0, x2), fmaxf(x4, x6));
    };

#define BODY(S, WV, DOSTAGE, DOPREF)                                          \
    __builtin_amdgcn_s_barrier(); SB0;                                        \
    if (DOSTAGE) stageG((S) + 2);                                             \
    ldgf(gfB, (const char*)&sG[(S) % 3][0] + 8192 + lane * 16);               \
    mmcl(gfA, (S));                                                           \
    asm volatile("s_waitcnt vmcnt(" #WV ")" ::: "memory"); SB0;               \
    if (DOPREF) ldgf(gfA, (const char*)&sG[((S) + 1) % 3][0] + lane * 16);    \
    {                                                                         \
        float t0 = red16(acc0), t1 = red16(acc1);                             \
        mmcl(gfB, (S) + 100);                                                 \
        t0 = fmaxf(t0, red16(acc0)); t1 = fmaxf(t1, red16(acc1));             \
        t0 = fmaxf(t0, __shfl_xor(t0, 32));                                   \
        t1 = fmaxf(t1, __shfl_xor(t1, 32));                                   \
        const int n = bn * 16 + (S);                                          \
        const float sv = hi ? t1 : t0;                                        \
        out[(size_t)(m0 + hi) * 4096 + n * 64 + h * 32 + l31] =               \
            fmaxf(sv, 0.f) + EPS_ADD;                                         \
    }

#pragma unroll 1
    for (int rep = 0; rep < REP; ++rep) {
        stageG(0);
        stageG(1);
        asm volatile("s_waitcnt vmcnt(4)" ::: "memory");
        __builtin_amdgcn_s_barrier(); SB0;
        ldgf(gfA, (const char*)&sG[0][0] + lane * 16);

        BODY(0, 4, 1, 1)
        BODY(1, 5, 1, 1)
        BODY(2, 5, 1, 1)
        BODY(3, 5, 1, 1)
        BODY(4, 5, 1, 1)
        BODY(5, 5, 1, 1)
        BODY(6, 5, 1, 1)
        BODY(7, 5, 1, 1)
        BODY(8, 5, 1, 1)
        BODY(9, 5, 1, 1)
        BODY(10, 5, 1, 1)
        BODY(11, 5, 1, 1)
        BODY(12, 5, 1, 1)
        BODY(13, 5, 1, 1)
        BODY(14, 1, 0, 1)
        BODY(15, 2, 0, 0)
    }
#undef BODY
}

// ---------------------------------------------------------------------------
extern "C" void kernel_launch(void* const* d_in, const int* in_sizes, int n_in,
                              void* d_out, int out_size, void* d_ws, size_t ws_size,
                              hipStream_t stream) {
    const float* A  = (const float*)d_in[0];
    const float* B  = (const float*)d_in[1];
    const float* Wg = (const float*)d_in[2];
    float* out = (float*)d_out;

    bf16* Afrag = (bf16*)d_ws;
    bf16* Gfrag = (bf16*)((char*)d_ws + (size_t)Mdim * Pdim * Cdim * sizeof(bf16));

    prep_kernel<<<768, 256, 0, stream>>>(A, B, Wg, Afrag, Gfrag);
    // ablation probes (garbage stores, overwritten by the final full kernel)
    gemm_probe<1><<<512, 256, 0, stream>>>(Afrag, Gfrag, out);  // no MFMA
    gemm_probe<2><<<512, 256, 0, stream>>>(Afrag, Gfrag, out);  // no ds_read
    gemm_probe<3><<<512, 256, 0, stream>>>(Afrag, Gfrag, out);  // no stage
    // the real kernel — byte-identical v16 semantics, overwrites all of out
    gemm_probe<0><<<512, 256, 0, stream>>>(Afrag, Gfrag, out);
}

// Round 21
// 51.615 us; speedup vs baseline: 3.9884x; 3.9884x over previous
//
#include <hip/hip_runtime.h>
#include <hip/hip_bf16.h>
#include <stdint.h>

typedef __attribute__((ext_vector_type(8))) short bf16x8;
typedef __attribute__((ext_vector_type(16))) float f32x16;
using bf16 = __hip_bfloat16;

static constexpr int Mdim = 512;   // A batch
static constexpr int Ndim = 64;    // B batch
static constexpr int Cdim = 128;   // channels (K of the GEMM)
static constexpr int Pdim = 64;    // H*W positions
static constexpr float EPS_ADD = 0.001f;

#define SB0 __builtin_amdgcn_sched_barrier(0)

// ---------------------------------------------------------------------------
// async global->LDS, 16B per lane
// ---------------------------------------------------------------------------
__device__ __forceinline__ void gll16(const void* gsrc, void* ldst) {
    const __attribute__((address_space(1))) unsigned int* g =
        (const __attribute__((address_space(1))) unsigned int*)gsrc;
    __attribute__((address_space(3))) unsigned int* l =
        (__attribute__((address_space(3))) unsigned int*)(uintptr_t)ldst;
    __builtin_amdgcn_global_load_lds(g, l, 16, 0, 0);
}

// ---------------------------------------------------------------------------
// prep (fused, UNCHANGED — verified): fragment-ordered outputs.
//   A-tile (per m): idx = h*4096 + ks*512 + lane*8 + e
//   G-tile (per n): idx = qt*4096 + ks*512 + lane*8 + e
// ---------------------------------------------------------------------------
__global__ void prep_kernel(const float* __restrict__ A, const float* __restrict__ B,
                            const float* __restrict__ Wg,
                            bf16* __restrict__ Afrag, bf16* __restrict__ Gfrag) {
    __shared__ float lds[128 * 65];
    const int t = threadIdx.x;

    if (blockIdx.x < 512) {
        const int m = blockIdx.x;
        const float* __restrict__ Am = A + (size_t)m * (Cdim * Pdim);
#pragma unroll
        for (int i = 0; i < 8; ++i) {
            int v = t + i * 256;
            int gidx = v * 4;
            int c = gidx >> 6, p = gidx & 63;
            float4 val = *reinterpret_cast<const float4*>(Am + gidx);
            float* dst = &lds[c * 65 + p];
            dst[0] = val.x; dst[1] = val.y; dst[2] = val.z; dst[3] = val.w;
        }
        __syncthreads();

        unsigned* __restrict__ dst32 = (unsigned*)(Afrag + (size_t)m * 8192);
#pragma unroll
        for (int i = 0; i < 16; ++i) {
            int pr = t + i * 256;
            int p = pr >> 6;
            int c = (pr & 63) << 1;
            float f0 = lds[c * 65 + p];
            float f1 = lds[(c + 1) * 65 + p];
            union { bf16 hh[2]; unsigned u; } pk;
            pk.hh[0] = __float2bfloat16(f0);
            pk.hh[1] = __float2bfloat16(f1);
            int h = p >> 5, l31 = p & 31;
            int ks = c >> 4, hi = (c >> 3) & 1, e = c & 7;
            dst32[h * 2048 + ks * 256 + hi * 128 + l31 * 4 + (e >> 1)] = pk.u;
        }
    } else {
        const int nb = blockIdx.x - 512;
        const int n  = nb >> 2;
        const int q0 = (nb & 3) * 16;
        const float* __restrict__ Bn = B + (size_t)n * (Cdim * Pdim);
#pragma unroll
        for (int i = 0; i < 8; ++i) {
            int v = t + i * 256;
            int gidx = v * 4;
            int c = gidx >> 6, q = gidx & 63;
            float4 val = *reinterpret_cast<const float4*>(Bn + gidx);
            float* dst = &lds[c * 65 + q];
            dst[0] = val.x; dst[1] = val.y; dst[2] = val.z; dst[3] = val.w;
        }
        __syncthreads();

        const int d  = t & 127;
        const int qb = q0 + (t >> 7) * 8;
        float acc[8] = {0.f, 0.f, 0.f, 0.f, 0.f, 0.f, 0.f, 0.f};
        for (int c = 0; c < 128; ++c) {
            float w = Wg[c * 128 + d];
#pragma unroll
            for (int qi = 0; qi < 8; ++qi)
                acc[qi] = fmaf(lds[c * 65 + qb + qi], w, acc[qi]);
        }
        bf16* __restrict__ gdst = Gfrag + (size_t)n * 8192;
        const int ks = d >> 4, hi = (d >> 3) & 1, e = d & 7;
#pragma unroll
        for (int qi = 0; qi < 8; ++qi) {
            int q = qb + qi;
            int qt = q >> 5, l31 = q & 31;
            gdst[qt * 4096 + ks * 512 + hi * 256 + l31 * 8 + e] = __float2bfloat16(acc[qi]);
        }
    }
}

// ---------------------------------------------------------------------------
// gemm_max v18: TLP fix per the r20 ablation (three ~14us SERIAL legs ->
// overlap them via 4+ independent blocks/CU, not via intra-wave scheduling).
//  - v16 dual-gf body; 8 n-steps/block; 2 rolling LDS bufs (32KB);
//    grid 1024 = 8 bn x 128 mg -> 4 blocks/CU EXACT (no tail).
//  - __launch_bounds__(256,3): cap 170 VGPR (v16 compiled at 88 -> safe);
//    LDS 160/32=5, VGPR 512/~90=5 -> HW can resident 4-5 blocks/CU.
// Ledger (per-wave events: stage 4 gll16 + 1 store; body order:
//   stage(s+1) -> WAITV -> barrier -> ds_reads/MFMA/reduce -> store):
//   prologue: A(16)+stage0(4) -> WAITV(0); barrier.
//   B0: stage(1); WAITV(4) [trivial]; B1..B6: entry queue = stage(s)(4),
//   store(s-1)(1), stage(s+1)(4) -> WAITV(5) drains stage(s).
//   B7: no stage; queue = stage(7)(4), store(6)(1) -> WAITV(1).
// Buffer safety (dist-1, one barrier/step): stage(s+1) overwrites the buf
//   read in body s-1; those reads register-completed before their waves
//   reached this barrier (lgkm waits precede their MFMAs precede barrier).
// MFMA 32x32x16, mfma(G,A): D col = lane&31 = p, row = q (m74/m101).
// bid%8 = mg%8 -> same-A blocks share an XCD L2.
// ---------------------------------------------------------------------------
__global__ __launch_bounds__(256, 3)
void gemm_max_kernel(const bf16* __restrict__ Afrag, const bf16* __restrict__ Gfrag,
                     float* __restrict__ out) {
    __shared__ bf16 sG[2][8192];          // 2 x 16KB rolling, fragment order
    const int tid  = threadIdx.x;
    const int lane = tid & 63;
    const int wv   = tid >> 6;            // 0..3
    const int mi = wv >> 1, h = wv & 1;   // wave: m-pair index, p-half
    const int l31 = lane & 31, hi = lane >> 5;
    const int mg = blockIdx.x & 127;      // 128 m-groups of 4
    const int bn = blockIdx.x >> 7;       // 8 n-groups of 8
    const int m0 = mg * 4 + mi * 2;       // wave handles m0, m0+1

    // ---- A resident: 16 coalesced 1KB loads (oldest vmcnt events) ----
    bf16x8 a[2][8];                       // [m-sub][ks]
#pragma unroll
    for (int u = 0; u < 2; ++u) {
        const bf16* Ap = Afrag + (size_t)(m0 + u) * 8192 + h * 4096 + lane * 8;
#pragma unroll
        for (int ks = 0; ks < 8; ++ks)
            a[u][ks] = *reinterpret_cast<const bf16x8*>(Ap + ks * 512);
    }
    asm volatile("" ::: "memory");        // pin A-loads before stage issues

    const char* Gsrc = (const char*)(Gfrag + (size_t)(bn * 8) * 8192);
    auto stageG = [&](int s) {            // 16KB: 4 x gll16 per thread
        char* dst = (char*)&sG[s & 1][0];
        const char* src = Gsrc + (size_t)s * 16384;
#pragma unroll
        for (int i = 0; i < 4; ++i) {
            int f = (i * 256 + tid) * 16;
            gll16(src + f, dst + f);
        }
    };

    const f32x16 z16 = {0.f,0.f,0.f,0.f,0.f,0.f,0.f,0.f,0.f,0.f,0.f,0.f,0.f,0.f,0.f,0.f};
    f32x16 acc0, acc1;
    bf16x8 gf0[8], gf1[8];

    auto ldgf = [&](bf16x8 (&g)[8], const char* base) {
#pragma unroll
        for (int ks = 0; ks < 8; ++ks)
            g[ks] = *reinterpret_cast<const bf16x8*>(base + ks * 1024);
    };
    auto mmcl = [&](const bf16x8 (&gf)[8]) {
        __builtin_amdgcn_s_setprio(1);
        acc0 = __builtin_amdgcn_mfma_f32_32x32x16_bf16(gf[0], a[0][0], z16, 0, 0, 0);
        acc1 = __builtin_amdgcn_mfma_f32_32x32x16_bf16(gf[0], a[1][0], z16, 0, 0, 0);
#pragma unroll
        for (int ks = 1; ks < 8; ++ks) {
            acc0 = __builtin_amdgcn_mfma_f32_32x32x16_bf16(gf[ks], a[0][ks], acc0, 0, 0, 0);
            acc1 = __builtin_amdgcn_mfma_f32_32x32x16_bf16(gf[ks], a[1][ks], acc1, 0, 0, 0);
        }
        __builtin_amdgcn_s_setprio(0);
    };
    auto red16 = [&](const f32x16& v) -> float {
        float x0 = fmaxf(v[0], v[1]),  x1 = fmaxf(v[2], v[3]);
        float x2 = fmaxf(v[4], v[5]),  x3 = fmaxf(v[6], v[7]);
        float x4 = fmaxf(v[8], v[9]),  x5 = fmaxf(v[10], v[11]);
        float x6 = fmaxf(v[12], v[13]), x7 = fmaxf(v[14], v[15]);
        x0 = fmaxf(x0, x1); x2 = fmaxf(x2, x3);
        x4 = fmaxf(x4, x5); x6 = fmaxf(x6, x7);
        return fmaxf(fmaxf(x0, x2), fmaxf(x4, x6));
    };

#define BODY(S, WV, DOSTAGE)                                                  \
    if (DOSTAGE) stageG((S) + 1);                                             \
    asm volatile("s_waitcnt vmcnt(" #WV ")" ::: "memory");                    \
    __builtin_amdgcn_s_barrier(); SB0;                                        \
    ldgf(gf0, (const char*)&sG[(S) & 1][0] + lane * 16);                      \
    ldgf(gf1, (const char*)&sG[(S) & 1][0] + 8192 + lane * 16);               \
    mmcl(gf0);                                                                \
    {                                                                         \
        float t0 = red16(acc0), t1 = red16(acc1);                             \
        mmcl(gf1);                                                            \
        t0 = fmaxf(t0, red16(acc0)); t1 = fmaxf(t1, red16(acc1));             \
        t0 = fmaxf(t0, __shfl_xor(t0, 32));                                   \
        t1 = fmaxf(t1, __shfl_xor(t1, 32));                                   \
        const int n = bn * 8 + (S);                                           \
        const float sv = hi ? t1 : t0;                                        \
        out[(size_t)(m0 + hi) * 4096 + n * 64 + h * 32 + l31] =               \
            fmaxf(sv, 0.f) + EPS_ADD;                                         \
    }

    // ---- prologue: stage(0); drain A + stage0 completely (once) ----
    stageG(0);
    asm volatile("s_waitcnt vmcnt(0)" ::: "memory");
    __builtin_amdgcn_s_barrier(); SB0;

    BODY(0, 4, 1)
    BODY(1, 5, 1)
    BODY(2, 5, 1)
    BODY(3, 5, 1)
    BODY(4, 5, 1)
    BODY(5, 5, 1)
    BODY(6, 5, 1)
    BODY(7, 1, 0)
#undef BODY
}

// ---------------------------------------------------------------------------
extern "C" void kernel_launch(void* const* d_in, const int* in_sizes, int n_in,
                              void* d_out, int out_size, void* d_ws, size_t ws_size,
                              hipStream_t stream) {
    const float* A  = (const float*)d_in[0];
    const float* B  = (const float*)d_in[1];
    const float* Wg = (const float*)d_in[2];
    float* out = (float*)d_out;

    bf16* Afrag = (bf16*)d_ws;                                      // 512 x 8192 bf16 = 8 MiB
    bf16* Gfrag = (bf16*)((char*)d_ws + (size_t)Mdim * Pdim * Cdim * sizeof(bf16)); // 64 x 8192 bf16

    prep_kernel<<<768, 256, 0, stream>>>(A, B, Wg, Afrag, Gfrag);
    gemm_max_kernel<<<1024, 256, 0, stream>>>(Afrag, Gfrag, out);   // 8 bn x 128 mg
}

// Round 22
// 45.398 us; speedup vs baseline: 4.5345x; 1.1369x over previous
//
#include <hip/hip_runtime.h>
#include <hip/hip_bf16.h>
#include <stdint.h>

typedef __attribute__((ext_vector_type(8))) short bf16x8;
typedef __attribute__((ext_vector_type(16))) float f32x16;
using bf16 = __hip_bfloat16;

static constexpr int Mdim = 512;   // A batch
static constexpr int Ndim = 64;    // B batch
static constexpr int Cdim = 128;   // channels (K of the GEMM)
static constexpr int Pdim = 64;    // H*W positions
static constexpr float EPS_ADD = 0.001f;

// ---------------------------------------------------------------------------
// async global->LDS, 16B per lane
// ---------------------------------------------------------------------------
__device__ __forceinline__ void gll16(const void* gsrc, void* ldst) {
    const __attribute__((address_space(1))) unsigned int* g =
        (const __attribute__((address_space(1))) unsigned int*)gsrc;
    __attribute__((address_space(3))) unsigned int* l =
        (__attribute__((address_space(3))) unsigned int*)(uintptr_t)ldst;
    __builtin_amdgcn_global_load_lds(g, l, 16, 0, 0);
}

// ---------------------------------------------------------------------------
// prep (fused, UNCHANGED — verified): fragment-ordered outputs.
//   A-tile (per m): idx = h*4096 + ks*512 + lane*8 + e
//   G-tile (per n): idx = qt*4096 + ks*512 + lane*8 + e
// ---------------------------------------------------------------------------
__global__ void prep_kernel(const float* __restrict__ A, const float* __restrict__ B,
                            const float* __restrict__ Wg,
                            bf16* __restrict__ Afrag, bf16* __restrict__ Gfrag) {
    __shared__ float lds[128 * 65];
    const int t = threadIdx.x;

    if (blockIdx.x < 512) {
        const int m = blockIdx.x;
        const float* __restrict__ Am = A + (size_t)m * (Cdim * Pdim);
#pragma unroll
        for (int i = 0; i < 8; ++i) {
            int v = t + i * 256;
            int gidx = v * 4;
            int c = gidx >> 6, p = gidx & 63;
            float4 val = *reinterpret_cast<const float4*>(Am + gidx);
            float* dst = &lds[c * 65 + p];
            dst[0] = val.x; dst[1] = val.y; dst[2] = val.z; dst[3] = val.w;
        }
        __syncthreads();

        unsigned* __restrict__ dst32 = (unsigned*)(Afrag + (size_t)m * 8192);
#pragma unroll
        for (int i = 0; i < 16; ++i) {
            int pr = t + i * 256;
            int p = pr >> 6;
            int c = (pr & 63) << 1;
            float f0 = lds[c * 65 + p];
            float f1 = lds[(c + 1) * 65 + p];
            union { bf16 hh[2]; unsigned u; } pk;
            pk.hh[0] = __float2bfloat16(f0);
            pk.hh[1] = __float2bfloat16(f1);
            int h = p >> 5, l31 = p & 31;
            int ks = c >> 4, hi = (c >> 3) & 1, e = c & 7;
            dst32[h * 2048 + ks * 256 + hi * 128 + l31 * 4 + (e >> 1)] = pk.u;
        }
    } else {
        const int nb = blockIdx.x - 512;
        const int n  = nb >> 2;
        const int q0 = (nb & 3) * 16;
        const float* __restrict__ Bn = B + (size_t)n * (Cdim * Pdim);
#pragma unroll
        for (int i = 0; i < 8; ++i) {
            int v = t + i * 256;
            int gidx = v * 4;
            int c = gidx >> 6, q = gidx & 63;
            float4 val = *reinterpret_cast<const float4*>(Bn + gidx);
            float* dst = &lds[c * 65 + q];
            dst[0] = val.x; dst[1] = val.y; dst[2] = val.z; dst[3] = val.w;
        }
        __syncthreads();

        const int d  = t & 127;
        const int qb = q0 + (t >> 7) * 8;
        float acc[8] = {0.f, 0.f, 0.f, 0.f, 0.f, 0.f, 0.f, 0.f};
        for (int c = 0; c < 128; ++c) {
            float w = Wg[c * 128 + d];
#pragma unroll
            for (int qi = 0; qi < 8; ++qi)
                acc[qi] = fmaf(lds[c * 65 + qb + qi], w, acc[qi]);
        }
        bf16* __restrict__ gdst = Gfrag + (size_t)n * 8192;
        const int ks = d >> 4, hi = (d >> 3) & 1, e = d & 7;
#pragma unroll
        for (int qi = 0; qi < 8; ++qi) {
            int q = qb + qi;
            int qt = q >> 5, l31 = q & 31;
            gdst[qt * 4096 + ks * 512 + hi * 256 + l31 * 8 + e] = __float2bfloat16(acc[qi]);
        }
    }
}

// ---------------------------------------------------------------------------
// gemm_max v19: the V3-probe shape made real — staging hoisted OUT of the
// loop (r20 ablation: no-stage variant = 27.3us/rep vs full 42, MfmaUtil 56%).
//  - Block = 4 waves (mi,h); BM=4 m's (a[2][8]/wave resident), BN=4 n's.
//  - G for all 4 n's (64KB) staged ONCE in the prologue (16 gll16/thread);
//    ONE vmcnt(0)+barrier; then 4 free-running bodies of pure
//    {16 ds_read (static offsets) -> 32 MFMA -> reduce -> store}.
//    NO steady-state barriers / WAITV / setprio / sched_barrier.
//  - sG is read-only after the barrier -> no overwrite hazards at all.
//  - Grid 2048 = 16 bn x 128 mg; bid%8 = mg%8 (same-A blocks on one XCD).
//    LDS 64KB -> 2 blocks/CU; 8 block-slots/CU so prologues of successive
//    blocks overlap other blocks' compute.
// MFMA 32x32x16, mfma(G,A): D col = lane&31 = p, row = q (m74/m101).
// Epilogue per body: in-lane 16-max x2, online max over qt, shfl_xor(32)
// fold, 1 store per lane (lane (hi,l31) stores m-sub m0+hi).
// ---------------------------------------------------------------------------
__global__ __launch_bounds__(256, 2)
void gemm_max_kernel(const bf16* __restrict__ Afrag, const bf16* __restrict__ Gfrag,
                     float* __restrict__ out) {
    __shared__ bf16 sG[4][8192];          // 64KB static, fragment order
    const int tid  = threadIdx.x;
    const int lane = tid & 63;
    const int wv   = tid >> 6;            // 0..3
    const int mi = wv >> 1, h = wv & 1;   // wave: m-pair index, p-half
    const int l31 = lane & 31, hi = lane >> 5;
    const int mg = blockIdx.x & 127;      // 128 m-groups of 4
    const int bn = blockIdx.x >> 7;       // 16 n-groups of 4
    const int m0 = mg * 4 + mi * 2;       // wave handles m0, m0+1

    // ---- prologue: A-loads + full G-stage, one drain, one barrier ----
    bf16x8 a[2][8];                       // [m-sub][ks]
#pragma unroll
    for (int u = 0; u < 2; ++u) {
        const bf16* Ap = Afrag + (size_t)(m0 + u) * 8192 + h * 4096 + lane * 8;
#pragma unroll
        for (int ks = 0; ks < 8; ++ks)
            a[u][ks] = *reinterpret_cast<const bf16x8*>(Ap + ks * 512);
    }
    {
        const char* Gsrc = (const char*)(Gfrag + (size_t)(bn * 4) * 8192);
#pragma unroll
        for (int i = 0; i < 16; ++i) {
            int f = (i * 256 + tid) * 16;
            gll16(Gsrc + f, (char*)sG + f);
        }
    }
    asm volatile("s_waitcnt vmcnt(0)" ::: "memory");
    __builtin_amdgcn_s_barrier();
    __builtin_amdgcn_sched_barrier(0);

    const f32x16 z16 = {0.f,0.f,0.f,0.f,0.f,0.f,0.f,0.f,0.f,0.f,0.f,0.f,0.f,0.f,0.f,0.f};
    f32x16 acc0, acc1;
    bf16x8 gf0[8], gf1[8];

    auto ldgf = [&](bf16x8 (&g)[8], const char* base) {
#pragma unroll
        for (int ks = 0; ks < 8; ++ks)
            g[ks] = *reinterpret_cast<const bf16x8*>(base + ks * 1024);
    };
    auto mmcl = [&](const bf16x8 (&gf)[8]) {
        acc0 = __builtin_amdgcn_mfma_f32_32x32x16_bf16(gf[0], a[0][0], z16, 0, 0, 0);
        acc1 = __builtin_amdgcn_mfma_f32_32x32x16_bf16(gf[0], a[1][0], z16, 0, 0, 0);
#pragma unroll
        for (int ks = 1; ks < 8; ++ks) {
            acc0 = __builtin_amdgcn_mfma_f32_32x32x16_bf16(gf[ks], a[0][ks], acc0, 0, 0, 0);
            acc1 = __builtin_amdgcn_mfma_f32_32x32x16_bf16(gf[ks], a[1][ks], acc1, 0, 0, 0);
        }
    };
    auto red16 = [&](const f32x16& v) -> float {
        float x0 = fmaxf(v[0], v[1]),  x1 = fmaxf(v[2], v[3]);
        float x2 = fmaxf(v[4], v[5]),  x3 = fmaxf(v[6], v[7]);
        float x4 = fmaxf(v[8], v[9]),  x5 = fmaxf(v[10], v[11]);
        float x6 = fmaxf(v[12], v[13]), x7 = fmaxf(v[14], v[15]);
        x0 = fmaxf(x0, x1); x2 = fmaxf(x2, x3);
        x4 = fmaxf(x4, x5); x6 = fmaxf(x6, x7);
        return fmaxf(fmaxf(x0, x2), fmaxf(x4, x6));
    };

#pragma unroll
    for (int s = 0; s < 4; ++s) {
        const char* gb = (const char*)sG + s * 16384 + lane * 16;
        ldgf(gf0, gb);            // qt0, compile-time LDS offsets
        ldgf(gf1, gb + 8192);     // qt1
        mmcl(gf0);
        float t0 = red16(acc0), t1 = red16(acc1);
        mmcl(gf1);
        t0 = fmaxf(t0, red16(acc0));
        t1 = fmaxf(t1, red16(acc1));
        t0 = fmaxf(t0, __shfl_xor(t0, 32));
        t1 = fmaxf(t1, __shfl_xor(t1, 32));
        const int n = bn * 4 + s;
        const float sv = hi ? t1 : t0;
        out[(size_t)(m0 + hi) * 4096 + n * 64 + h * 32 + l31] =
            fmaxf(sv, 0.f) + EPS_ADD;
    }
}

// ---------------------------------------------------------------------------
extern "C" void kernel_launch(void* const* d_in, const int* in_sizes, int n_in,
                              void* d_out, int out_size, void* d_ws, size_t ws_size,
                              hipStream_t stream) {
    const float* A  = (const float*)d_in[0];
    const float* B  = (const float*)d_in[1];
    const float* Wg = (const float*)d_in[2];
    float* out = (float*)d_out;

    bf16* Afrag = (bf16*)d_ws;                                      // 512 x 8192 bf16 = 8 MiB
    bf16* Gfrag = (bf16*)((char*)d_ws + (size_t)Mdim * Pdim * Cdim * sizeof(bf16)); // 64 x 8192 bf16

    prep_kernel<<<768, 256, 0, stream>>>(A, B, Wg, Afrag, Gfrag);
    gemm_max_kernel<<<2048, 256, 0, stream>>>(Afrag, Gfrag, out);   // 16 bn x 128 mg
}